// Round 1
// baseline (1630.055 us; speedup 1.0000x reference)
//
#include <hip/hip_runtime.h>
#include <cstdint>
#include <cstddef>

#define S_LEN 250
#define BATCH 256
#define CIN   700
#define HID   256
#define OUT_N 20

// ---------------------------------------------------------------------------
// Kernel 1: input projection GEMM.
// P[(b*S+s)*512 + n] = x[b,s,:] . W_in_f[:,n]        + b_in_f[n]   (n < 256)
//                    = x[b,s,:] . W_in_b[:,n-256]    + b_in_b[n-256] (n >= 256)
// M = 64000, N = 512, K = 700, fp32, k-sequential FMA accumulation.
// ---------------------------------------------------------------------------
#define TM  128
#define TN  128
#define BKK 16

__global__ __launch_bounds__(256) void proj_gemm(
    const float* __restrict__ x,
    const float* __restrict__ Wf,
    const float* __restrict__ Wb,
    const float* __restrict__ biasf,
    const float* __restrict__ biasb,
    float* __restrict__ P)
{
    __shared__ float As[BKK][TM + 4];   // pad to 132 floats: aligned b128 rows
    __shared__ float Bs[BKK][TN];

    const int nt = blockIdx.x;          // 0..3
    const int mt = blockIdx.y;          // 0..499
    const int m0 = mt * TM;
    const int n0 = nt * TN;
    const float* W   = (n0 < HID) ? Wf : Wb;
    const float* bia = (n0 < HID) ? biasf : biasb;
    const int wc0 = n0 & (HID - 1);     // 0 or 128 within the selected W

    const int tid = threadIdx.x;
    const int tm = tid & 15, tn = tid >> 4;
    const int rm = tm * 8, rn = tn * 8;

    float acc[8][8];
#pragma unroll
    for (int i = 0; i < 8; i++)
#pragma unroll
        for (int j = 0; j < 8; j++) acc[i][j] = 0.f;

    const int a_kk = tid & 15;
    const int a_r0 = (tid >> 4) * 8;
    const int b_n  = tid & 127;
    const int b_k0 = (tid >> 7) * 8;

    for (int k0 = 0; k0 < CIN; k0 += BKK) {
#pragma unroll
        for (int i = 0; i < 8; i++) {
            int r = a_r0 + i;
            int k = k0 + a_kk;
            As[a_kk][r] = (k < CIN) ? x[(size_t)(m0 + r) * CIN + k] : 0.f;
        }
#pragma unroll
        for (int i = 0; i < 8; i++) {
            int kk = b_k0 + i;
            int k = k0 + kk;
            Bs[kk][b_n] = (k < CIN) ? W[(size_t)k * HID + wc0 + b_n] : 0.f;
        }
        __syncthreads();
#pragma unroll
        for (int kk = 0; kk < BKK; kk++) {
            float a[8], bv[8];
#pragma unroll
            for (int i = 0; i < 8; i++) a[i] = As[kk][rm + i];
#pragma unroll
            for (int j = 0; j < 8; j++) bv[j] = Bs[kk][rn + j];
#pragma unroll
            for (int i = 0; i < 8; i++)
#pragma unroll
                for (int j = 0; j < 8; j++)
                    acc[i][j] = __fmaf_rn(a[i], bv[j], acc[i][j]);
        }
        __syncthreads();
    }

    float bb_[8];
#pragma unroll
    for (int j = 0; j < 8; j++) bb_[j] = bia[wc0 + rn + j];
#pragma unroll
    for (int i = 0; i < 8; i++) {
        float4 v0, v1;
        v0.x = __fadd_rn(acc[i][0], bb_[0]);
        v0.y = __fadd_rn(acc[i][1], bb_[1]);
        v0.z = __fadd_rn(acc[i][2], bb_[2]);
        v0.w = __fadd_rn(acc[i][3], bb_[3]);
        v1.x = __fadd_rn(acc[i][4], bb_[4]);
        v1.y = __fadd_rn(acc[i][5], bb_[5]);
        v1.z = __fadd_rn(acc[i][6], bb_[6]);
        v1.w = __fadd_rn(acc[i][7], bb_[7]);
        size_t base = (size_t)(m0 + rm + i) * 512 + (size_t)(n0 + rn);
        *(float4*)&P[base]     = v0;
        *(float4*)&P[base + 4] = v1;
    }
}

// ---------------------------------------------------------------------------
// Kernel 2: the sequential scan. One block per batch element (independent
// dynamics), 512 threads: tid<256 = forward neuron tid, tid>=256 = backward
// neuron tid-256. Spikes are binary -> recurrent matmul is an ordered
// gather-sum of W_rec rows (bit-exact vs k-sequential fp32 GEMM).
// FUSED=true computes the input projection on the fly (ws too small).
// ---------------------------------------------------------------------------
template<bool FUSED>
__global__ __launch_bounds__(512) void scan_kernel(
    const float* __restrict__ P,
    const float* __restrict__ x,
    const float* __restrict__ Winf, const float* __restrict__ binf,
    const float* __restrict__ Winb, const float* __restrict__ binb,
    const float* __restrict__ Wrecf, const float* __restrict__ brecf,
    const float* __restrict__ taumf, const float* __restrict__ tauaf,
    const float* __restrict__ Wrecb, const float* __restrict__ brecb,
    const float* __restrict__ taumb, const float* __restrict__ tauab,
    const float* __restrict__ Wout, const float* __restrict__ bout,
    const float* __restrict__ taumo,
    float* __restrict__ out)
{
    const int b   = blockIdx.x;
    const int tid = threadIdx.x;
    const int h   = tid & (HID - 1);
    const bool fw = tid < HID;

    __shared__ float Wout_s[512 * OUT_N];          // 40 KB
    __shared__ unsigned long long masks[8];
    __shared__ int pops[8];
    __shared__ int cnts[2];                        // [0]=cnt_fw, [1]=cnt_all
    __shared__ unsigned short list[512];           // sorted merged spike idx
    __shared__ float part[16][OUT_N];
    __shared__ float memo_s[OUT_N];
    __shared__ float red2[2];
    __shared__ float xs[2][CIN];                   // only used when FUSED

    for (int i = tid; i < 512 * OUT_N; i += 512) Wout_s[i] = Wout[i];
    if (tid < 8) { masks[tid] = 0ULL; pops[tid] = 0; }
    if (tid < 2) cnts[tid] = 0;

    const float* Wrec = fw ? Wrecf : Wrecb;
    const float* Wcol = Wrec + h;
    const float brc   = fw ? brecf[h] : brecb[h];
    const float alpha = expf(__fdiv_rn(-1.f, fw ? taumf[h] : taumb[h]));
    const float ro    = expf(__fdiv_rn(-1.f, fw ? tauaf[h] : tauab[h]));
    const float omA   = __fsub_rn(1.f, alpha);
    const float omR   = __fsub_rn(1.f, ro);
    const float* Win  = fw ? Winf : Winb;
    const float* Wic  = Win + h;
    const float bi    = fw ? binf[h] : binb[h];

    float alpha_o = 0.f, omO = 0.f, bo = 0.f, momo = 0.f;
    if (tid < OUT_N) {
        alpha_o = expf(__fdiv_rn(-1.f, taumo[tid]));
        omO = __fsub_rn(1.f, alpha_o);
        bo  = bout[tid];
    }

    float mem = 0.f, bbv = 0.01f, spk = 0.f;

    __syncthreads();

    for (int s = 0; s < S_LEN; s++) {
        float pv;
        if (FUSED) {
            const float* xrf = x + ((size_t)b * S_LEN + s) * CIN;
            const float* xrb = x + ((size_t)b * S_LEN + (S_LEN - 1 - s)) * CIN;
            for (int c = tid; c < CIN; c += 512) {
                xs[0][c] = xrf[c];
                xs[1][c] = xrb[c];
            }
            __syncthreads();
            const float* xr = fw ? xs[0] : xs[1];
            float a0 = 0.f;
            int c = 0;
            for (; c + 8 <= CIN; c += 8) {
                float w[8];
#pragma unroll
                for (int u = 0; u < 8; u++) w[u] = Wic[(size_t)(c + u) * HID];
#pragma unroll
                for (int u = 0; u < 8; u++) a0 = __fmaf_rn(xr[c + u], w[u], a0);
            }
            for (; c < CIN; c++) a0 = __fmaf_rn(xr[c], Wic[(size_t)c * HID], a0);
            pv = __fadd_rn(a0, bi);
        } else {
            const int srow = fw ? s : (S_LEN - 1 - s);
            pv = P[((size_t)b * S_LEN + srow) * 512 + tid];
        }

        // ---- recurrent gather: ordered sum of W_rec rows for spiking h'
        const int cf = cnts[0], ca = cnts[1];
        const int i0 = fw ? 0 : cf;
        const int i1 = fw ? cf : ca;
        const int sub = fw ? 0 : HID;
        float acc = 0.f;
        int i = i0;
        for (; i + 8 <= i1; i += 8) {
            float w[8];
#pragma unroll
            for (int u = 0; u < 8; u++)
                w[u] = Wcol[(size_t)(list[i + u] - sub) << 8];
#pragma unroll
            for (int u = 0; u < 8; u++) acc = __fadd_rn(acc, w[u]);
        }
        for (; i < i1; i++)
            acc = __fadd_rn(acc, Wcol[(size_t)(list[i] - sub) << 8]);

        // ---- adaptive-LIF state update (rounding order matches reference)
        const float d  = __fadd_rn(__fadd_rn(pv, acc), brc);
        bbv = __fadd_rn(__fmul_rn(ro, bbv), __fmul_rn(omR, spk));
        const float thr = __fadd_rn(0.01f, __fmul_rn(1.8f, bbv));
        mem = __fsub_rn(__fadd_rn(__fmul_rn(mem, alpha), __fmul_rn(omA, d)),
                        __fmul_rn(thr, spk));
        const float v = __fsub_rn(mem, thr);
        const bool sp = v > 0.f;
        spk = sp ? 1.f : 0.f;

        unsigned long long bal = __ballot(sp);
        if ((tid & 63) == 0) {
            masks[tid >> 6] = bal;
            pops[tid >> 6]  = __popcll(bal);
        }
        __syncthreads();   // B1: masks(t) visible

        // build sorted merged spike index list (8 lanes, one mask word each)
        if (tid < 8) {
            int off = 0;
            for (int w2 = 0; w2 < tid; w2++) off += pops[w2];
            if (tid == 3) cnts[0] = off + pops[3];
            if (tid == 7) cnts[1] = off + pops[7];
            unsigned long long mm = masks[tid];
            const int base = tid << 6;
            while (mm) {
                int j = __ffsll(mm) - 1;
                list[off++] = (unsigned short)(base + j);
                mm &= (mm - 1);
            }
        }
        // readout partials: 16 segments of 32 merged neurons x 20 outputs
        if (tid < 320) {
            const int o   = tid % OUT_N;
            const int seg = tid / OUT_N;
            const unsigned int bits =
                (unsigned int)(masks[seg >> 1] >> ((seg & 1) * 32));
            float p = 0.f;
#pragma unroll
            for (int j = 0; j < 32; j++) {
                if ((bits >> j) & 1u)
                    p = __fadd_rn(p, Wout_s[(seg * 32 + j) * OUT_N + o]);
            }
            part[seg][o] = p;
        }
        __syncthreads();   // B2: list(t), partials(t) visible

        if (tid < OUT_N) {
            float ssum = part[0][tid];
#pragma unroll
            for (int g = 1; g < 16; g++) ssum = __fadd_rn(ssum, part[g][tid]);
            ssum = __fadd_rn(ssum, bo);
            momo = __fadd_rn(__fmul_rn(alpha_o, momo), __fmul_rn(omO, ssum));
        }
    }

    if (tid < OUT_N) memo_s[tid] = momo;
    __syncthreads();
    if (tid == 0) {
        float mx = memo_s[0];
        for (int o = 1; o < OUT_N; o++) mx = fmaxf(mx, memo_s[o]);
        float se = 0.f;
        for (int o = 0; o < OUT_N; o++) se += expf(__fsub_rn(memo_s[o], mx));
        red2[0] = mx;
        red2[1] = logf(se);
    }
    __syncthreads();
    if (tid < OUT_N)
        out[(size_t)b * OUT_N + tid] =
            __fsub_rn(__fsub_rn(memo_s[tid], red2[0]), red2[1]);
}

// ---------------------------------------------------------------------------
extern "C" void kernel_launch(void* const* d_in, const int* in_sizes, int n_in,
                              void* d_out, int out_size, void* d_ws, size_t ws_size,
                              hipStream_t stream) {
    const float* x         = (const float*)d_in[0];
    const float* W_in_f    = (const float*)d_in[1];
    const float* b_in_f    = (const float*)d_in[2];
    const float* W_rec_f   = (const float*)d_in[3];
    const float* b_rec_f   = (const float*)d_in[4];
    const float* tau_m_f   = (const float*)d_in[5];
    const float* tau_adp_f = (const float*)d_in[6];
    const float* W_in_b    = (const float*)d_in[7];
    const float* b_in_b    = (const float*)d_in[8];
    const float* W_rec_b   = (const float*)d_in[9];
    const float* b_rec_b   = (const float*)d_in[10];
    const float* tau_m_b   = (const float*)d_in[11];
    const float* tau_adp_b = (const float*)d_in[12];
    const float* W_out     = (const float*)d_in[13];
    const float* b_out     = (const float*)d_in[14];
    const float* tau_m_o   = (const float*)d_in[15];
    float* out = (float*)d_out;
    float* P   = (float*)d_ws;

    const size_t needP = (size_t)BATCH * S_LEN * 512 * sizeof(float);
    const bool fused = (d_ws == nullptr) || (ws_size < needP);

    if (!fused) {
        proj_gemm<<<dim3(4, 500), dim3(256), 0, stream>>>(
            x, W_in_f, W_in_b, b_in_f, b_in_b, P);
        scan_kernel<false><<<dim3(BATCH), dim3(512), 0, stream>>>(
            P, x, W_in_f, b_in_f, W_in_b, b_in_b,
            W_rec_f, b_rec_f, tau_m_f, tau_adp_f,
            W_rec_b, b_rec_b, tau_m_b, tau_adp_b,
            W_out, b_out, tau_m_o, out);
    } else {
        scan_kernel<true><<<dim3(BATCH), dim3(512), 0, stream>>>(
            nullptr, x, W_in_f, b_in_f, W_in_b, b_in_b,
            W_rec_f, b_rec_f, tau_m_f, tau_adp_f,
            W_rec_b, b_rec_b, tau_m_b, tau_adp_b,
            W_out, b_out, tau_m_o, out);
    }
}

// Round 2
// 916.329 us; speedup vs baseline: 1.7789x; 1.7789x over previous
//
#include <hip/hip_runtime.h>
#include <cstdint>
#include <cstddef>

#define S_LEN 250
#define BATCH 256
#define CIN   700
#define HID   256
#define OUT_N 20

// ---------------------------------------------------------------------------
// Kernel 1: input projection GEMM (fp32 vector ALU; no fp32 MFMA on CDNA4).
// P[(b*S+s)*512 + n] = x[b,s,:] . W_in_f[:,n]     + b_in_f[n]     (n < 256)
//                    = x[b,s,:] . W_in_b[:,n-256] + b_in_b[n-256] (n >= 256)
// M=64000, N=512, K=700. k-sequential FMA accumulation (order preserved).
// 128x128 tile, BK=16, 8x8 per thread in split-half fragments:
//   rows m0 + {tm*4..+3} and m0+64+{tm*4..+3}   (tm = tid&15)
//   cols n0 + {tn*4..+3} and n0+64+{tn*4..+3}   (tn = tid>>4)
// -> A-read: 16 consecutive float4 per 16-lane phase (conflict-free)
// -> B-read: 16-lane broadcast of consecutive float4 (conflict-free)
// ---------------------------------------------------------------------------
#define BKK 16
#define APAD 132

__global__ __launch_bounds__(256) void proj_gemm(
    const float* __restrict__ x,
    const float* __restrict__ Wf,
    const float* __restrict__ Wb,
    const float* __restrict__ biasf,
    const float* __restrict__ biasb,
    float* __restrict__ P)
{
    __shared__ float As[BKK][APAD];    // [k][m], rows 528 B (16B aligned)
    __shared__ float Bs[BKK][128];     // [k][n], rows 512 B

    const int nt = blockIdx.x;          // 0..3
    const int mt = blockIdx.y;          // 0..499
    const int m0 = mt * 128;
    const int n0 = nt * 128;
    const float* W   = (n0 < HID) ? Wf : Wb;
    const float* bia = (n0 < HID) ? biasf : biasb;
    const int wc0 = n0 & (HID - 1);     // 0 or 128 within selected W

    const int tid = threadIdx.x;
    const int tm = tid & 15, tn = tid >> 4;

    float acc[8][8];
#pragma unroll
    for (int i = 0; i < 8; i++)
#pragma unroll
        for (int j = 0; j < 8; j++) acc[i][j] = 0.f;

    // A staging map: thread -> (row ar, float4-slot aq), two row-halves
    const int ar = tid >> 2;            // 0..63
    const int aq = tid & 3;             // k-slot (4 floats)
    // B staging map: thread -> (k-row bk, float4-slot bn), two k-halves
    const int bn = tid & 31;            // 0..31 (n float4)
    const int bk = tid >> 5;            // 0..7

    for (int k0 = 0; k0 < CIN; k0 += BKK) {
        // ---- stage A: 128 rows x 16 k, float4 global loads, scalar LDS
#pragma unroll
        for (int half = 0; half < 2; half++) {
            const int r  = ar + half * 64;
            const int gk = k0 + aq * 4;
            float4 v = make_float4(0.f, 0.f, 0.f, 0.f);
            if (gk < CIN)   // CIN%4==0: float4 fully valid or fully invalid
                v = *(const float4*)&x[(size_t)(m0 + r) * CIN + gk];
            As[aq * 4 + 0][r] = v.x;
            As[aq * 4 + 1][r] = v.y;
            As[aq * 4 + 2][r] = v.z;
            As[aq * 4 + 3][r] = v.w;
        }
        // ---- stage B: 16 k x 128 n, float4 global loads, float4 LDS
#pragma unroll
        for (int half = 0; half < 2; half++) {
            const int kk = bk + half * 8;
            const int gk = k0 + kk;
            float4 v = make_float4(0.f, 0.f, 0.f, 0.f);
            if (gk < CIN)
                v = *(const float4*)&W[(size_t)gk * HID + wc0 + bn * 4];
            *(float4*)&Bs[kk][bn * 4] = v;
        }
        __syncthreads();
#pragma unroll
        for (int kk = 0; kk < BKK; kk++) {
            const float4 a0 = *(const float4*)&As[kk][tm * 4];
            const float4 a1 = *(const float4*)&As[kk][64 + tm * 4];
            const float4 b0 = *(const float4*)&Bs[kk][tn * 4];
            const float4 b1 = *(const float4*)&Bs[kk][64 + tn * 4];
            const float av[8] = {a0.x, a0.y, a0.z, a0.w, a1.x, a1.y, a1.z, a1.w};
            const float bv[8] = {b0.x, b0.y, b0.z, b0.w, b1.x, b1.y, b1.z, b1.w};
#pragma unroll
            for (int i = 0; i < 8; i++)
#pragma unroll
                for (int j = 0; j < 8; j++)
                    acc[i][j] = __fmaf_rn(av[i], bv[j], acc[i][j]);
        }
        __syncthreads();
    }

    float bb_[8];
#pragma unroll
    for (int j = 0; j < 8; j++)
        bb_[j] = bia[wc0 + (j >> 2) * 64 + tn * 4 + (j & 3)];
#pragma unroll
    for (int i = 0; i < 8; i++) {
        const int row = m0 + (i >> 2) * 64 + tm * 4 + (i & 3);
#pragma unroll
        for (int qj = 0; qj < 2; qj++) {
            float4 v;
            v.x = __fadd_rn(acc[i][qj * 4 + 0], bb_[qj * 4 + 0]);
            v.y = __fadd_rn(acc[i][qj * 4 + 1], bb_[qj * 4 + 1]);
            v.z = __fadd_rn(acc[i][qj * 4 + 2], bb_[qj * 4 + 2]);
            v.w = __fadd_rn(acc[i][qj * 4 + 3], bb_[qj * 4 + 3]);
            *(float4*)&P[(size_t)row * 512 + n0 + qj * 64 + tn * 4] = v;
        }
    }
}

// ---------------------------------------------------------------------------
// Kernel 2: sequential scan. One block per batch, 512 threads (tid<256 = fw
// neuron, tid>=256 = bw neuron). Spikes binary -> recurrent matmul is an
// ordered gather-sum of W_rec rows (bit-exact vs k-sequential fp32 GEMM).
// Readout integrator is linear in spikes & feeds nothing back -> run per-h
// leaky integrators in registers, reduce once at the end.
// ---------------------------------------------------------------------------
template<bool FUSED>
__global__ __launch_bounds__(512) void scan_kernel(
    const float* __restrict__ P,
    const float* __restrict__ x,
    const float* __restrict__ Winf, const float* __restrict__ binf,
    const float* __restrict__ Winb, const float* __restrict__ binb,
    const float* __restrict__ Wrecf, const float* __restrict__ brecf,
    const float* __restrict__ taumf, const float* __restrict__ tauaf,
    const float* __restrict__ Wrecb, const float* __restrict__ brecb,
    const float* __restrict__ taumb, const float* __restrict__ tauab,
    const float* __restrict__ Wout, const float* __restrict__ bout,
    const float* __restrict__ taumo,
    float* __restrict__ out)
{
    const int b   = blockIdx.x;
    const int tid = threadIdx.x;
    const int h   = tid & (HID - 1);
    const bool fw = tid < HID;
    const int lane = tid & 63;
    const int wv   = tid >> 6;          // wave 0..7

    __shared__ int pops[8];
    __shared__ int cnts[2][2];          // [buf][0]=cnt_fw, [1]=cnt_all
    __shared__ unsigned short list[2][512];
    __shared__ float part[8][OUT_N];
    __shared__ float memo_s[OUT_N];
    __shared__ float red2[2];
    __shared__ float xs[2][CIN];        // only used when FUSED

    if (tid < 2) { cnts[0][tid] = 0; }

    const float* Wrec = fw ? Wrecf : Wrecb;
    const float* Wcol = Wrec + h;
    const float brc   = fw ? brecf[h] : brecb[h];
    const float alpha = expf(__fdiv_rn(-1.f, fw ? taumf[h] : taumb[h]));
    const float ro    = expf(__fdiv_rn(-1.f, fw ? tauaf[h] : tauab[h]));
    const float omA   = __fsub_rn(1.f, alpha);
    const float omR   = __fsub_rn(1.f, ro);
    const float* Win  = fw ? Winf : Winb;
    const float* Wic  = Win + h;
    const float bi    = fw ? binf[h] : binb[h];

    // per-output leaky-integrator constants (register resident)
    float ao[OUT_N], omo[OUT_N], zacc[OUT_N];
#pragma unroll
    for (int o = 0; o < OUT_N; o++) {
        ao[o]   = expf(__fdiv_rn(-1.f, taumo[o]));
        omo[o]  = __fsub_rn(1.f, ao[o]);
        zacc[o] = 0.f;
    }

    float mem = 0.f, bbv = 0.01f, spk = 0.f;

    const unsigned long long below = (1ull << lane) - 1ull;

    __syncthreads();

    // prefetch step-0 projection
    float pv;
    if (!FUSED) {
        const int srow0 = fw ? 0 : (S_LEN - 1);
        pv = P[((size_t)b * S_LEN + srow0) * 512 + tid];
    }

    for (int s = 0; s < S_LEN; s++) {
        const int rbuf = s & 1, wbuf = rbuf ^ 1;

        float pv_next = 0.f;
        if (!FUSED) {
            const int sn   = (s + 1 < S_LEN) ? s + 1 : S_LEN - 1;
            const int srow = fw ? sn : (S_LEN - 1 - sn);
            pv_next = P[((size_t)b * S_LEN + srow) * 512 + tid];
        } else {
            const float* xrf = x + ((size_t)b * S_LEN + s) * CIN;
            const float* xrb = x + ((size_t)b * S_LEN + (S_LEN - 1 - s)) * CIN;
            for (int c = tid; c < CIN; c += 512) {
                xs[0][c] = xrf[c];
                xs[1][c] = xrb[c];
            }
            __syncthreads();
            const float* xr = fw ? xs[0] : xs[1];
            float a0 = 0.f;
            for (int c = 0; c < CIN; c += 4) {
                float w0 = Wic[(size_t)(c + 0) * HID];
                float w1 = Wic[(size_t)(c + 1) * HID];
                float w2 = Wic[(size_t)(c + 2) * HID];
                float w3 = Wic[(size_t)(c + 3) * HID];
                a0 = __fmaf_rn(xr[c + 0], w0, a0);
                a0 = __fmaf_rn(xr[c + 1], w1, a0);
                a0 = __fmaf_rn(xr[c + 2], w2, a0);
                a0 = __fmaf_rn(xr[c + 3], w3, a0);
            }
            pv = __fadd_rn(a0, bi);
        }

        // ---- recurrent gather: ordered sum of W_rec rows for spiking h'
        const int cf = cnts[rbuf][0], ca = cnts[rbuf][1];
        const int i0 = fw ? 0 : cf;
        const int i1 = fw ? cf : ca;
        const int sub = fw ? 0 : HID;
        float acc = 0.f;
        {
            int i = i0;
            for (; i + 8 <= i1; i += 8) {
                float w[8];
#pragma unroll
                for (int u = 0; u < 8; u++)
                    w[u] = Wcol[(size_t)(list[rbuf][i + u] - sub) << 8];
#pragma unroll
                for (int u = 0; u < 8; u++) acc = __fadd_rn(acc, w[u]);
            }
            for (; i < i1; i++)
                acc = __fadd_rn(acc, Wcol[(size_t)(list[rbuf][i] - sub) << 8]);
        }

        // ---- adaptive-LIF state update (rounding order matches reference)
        const float d  = __fadd_rn(__fadd_rn(pv, acc), brc);
        bbv = __fadd_rn(__fmul_rn(ro, bbv), __fmul_rn(omR, spk));
        const float thr = __fadd_rn(0.01f, __fmul_rn(1.8f, bbv));
        mem = __fsub_rn(__fadd_rn(__fmul_rn(mem, alpha), __fmul_rn(omA, d)),
                        __fmul_rn(thr, spk));
        const bool sp = __fsub_rn(mem, thr) > 0.f;
        spk = sp ? 1.f : 0.f;

        const unsigned long long bal = __ballot(sp);
        if (lane == 0) pops[wv] = __popcll(bal);
        __syncthreads();   // A: pops(t) visible

        // parallel rank-based sorted list build (ascending tid order)
        {
            int off = 0;
#pragma unroll
            for (int w2 = 0; w2 < 7; w2++)
                if (w2 < wv) off += pops[w2];
            if (sp) {
                off += __popcll(bal & below);
                list[wbuf][off] = (unsigned short)tid;
            }
        }
        if (tid == 0) {
            const int c0 = pops[0] + pops[1] + pops[2] + pops[3];
            cnts[wbuf][0] = c0;
            cnts[wbuf][1] = c0 + pops[4] + pops[5] + pops[6] + pops[7];
        }

        // ---- readout: per-h leaky integrator (linear, no feedback)
        const float sv = spk;
#pragma unroll
        for (int o = 0; o < OUT_N; o++)
            zacc[o] = __fmaf_rn(ao[o], zacc[o], __fmul_rn(omo[o], sv));

        if (!FUSED) pv = pv_next;
        __syncthreads();   // B: list(t), cnts(t) visible
    }

    // ---- final readout reduction: mem_o[o] = sum_h zacc_h[o]*W_out[h][o]
    //                                          + b_o*(1 - alpha_o^S)
#pragma unroll
    for (int o = 0; o < OUT_N; o++) {
        float v = __fmul_rn(zacc[o], Wout[(size_t)tid * OUT_N + o]);
#pragma unroll
        for (int d2 = 1; d2 < 64; d2 <<= 1)
            v += __shfl_xor(v, d2, 64);
        if (lane == 0) part[wv][o] = v;
    }
    __syncthreads();
    if (tid < OUT_N) {
        float tot = part[0][tid];
#pragma unroll
        for (int w2 = 1; w2 < 8; w2++) tot = __fadd_rn(tot, part[w2][tid]);
        const float aS = expf(__fdiv_rn(-(float)S_LEN, taumo[tid]));
        tot = __fadd_rn(tot, __fmul_rn(bout[tid], __fsub_rn(1.f, aS)));
        memo_s[tid] = tot;
    }
    __syncthreads();
    if (tid == 0) {
        float mx = memo_s[0];
        for (int o = 1; o < OUT_N; o++) mx = fmaxf(mx, memo_s[o]);
        float se = 0.f;
        for (int o = 0; o < OUT_N; o++) se += expf(__fsub_rn(memo_s[o], mx));
        red2[0] = mx;
        red2[1] = logf(se);
    }
    __syncthreads();
    if (tid < OUT_N)
        out[(size_t)b * OUT_N + tid] =
            __fsub_rn(__fsub_rn(memo_s[tid], red2[0]), red2[1]);
}

// ---------------------------------------------------------------------------
extern "C" void kernel_launch(void* const* d_in, const int* in_sizes, int n_in,
                              void* d_out, int out_size, void* d_ws, size_t ws_size,
                              hipStream_t stream) {
    const float* x         = (const float*)d_in[0];
    const float* W_in_f    = (const float*)d_in[1];
    const float* b_in_f    = (const float*)d_in[2];
    const float* W_rec_f   = (const float*)d_in[3];
    const float* b_rec_f   = (const float*)d_in[4];
    const float* tau_m_f   = (const float*)d_in[5];
    const float* tau_adp_f = (const float*)d_in[6];
    const float* W_in_b    = (const float*)d_in[7];
    const float* b_in_b    = (const float*)d_in[8];
    const float* W_rec_b   = (const float*)d_in[9];
    const float* b_rec_b   = (const float*)d_in[10];
    const float* tau_m_b   = (const float*)d_in[11];
    const float* tau_adp_b = (const float*)d_in[12];
    const float* W_out     = (const float*)d_in[13];
    const float* b_out     = (const float*)d_in[14];
    const float* tau_m_o   = (const float*)d_in[15];
    float* out = (float*)d_out;
    float* P   = (float*)d_ws;

    const size_t needP = (size_t)BATCH * S_LEN * 512 * sizeof(float);
    const bool fused = (d_ws == nullptr) || (ws_size < needP);

    if (!fused) {
        proj_gemm<<<dim3(4, 500), dim3(256), 0, stream>>>(
            x, W_in_f, W_in_b, b_in_f, b_in_b, P);
        scan_kernel<false><<<dim3(BATCH), dim3(512), 0, stream>>>(
            P, x, W_in_f, b_in_f, W_in_b, b_in_b,
            W_rec_f, b_rec_f, tau_m_f, tau_adp_f,
            W_rec_b, b_rec_b, tau_m_b, tau_adp_b,
            W_out, b_out, tau_m_o, out);
    } else {
        scan_kernel<true><<<dim3(BATCH), dim3(512), 0, stream>>>(
            nullptr, x, W_in_f, b_in_f, W_in_b, b_in_b,
            W_rec_f, b_rec_f, tau_m_f, tau_adp_f,
            W_rec_b, b_rec_b, tau_m_b, tau_adp_b,
            W_out, b_out, tau_m_o, out);
    }
}

// Round 3
// 900.394 us; speedup vs baseline: 1.8104x; 1.0177x over previous
//
#include <hip/hip_runtime.h>
#include <cstdint>
#include <cstddef>

#define S_LEN 250
#define BATCH 256
#define CIN   700
#define HID   256
#define OUT_N 20

// ---------------------------------------------------------------------------
// Kernel 1: input projection GEMM (fp32 vector ALU; no fp32 MFMA on CDNA4).
// P[(b*S+s)*512 + n] = x[b,s,:] . W_in_f[:,n]     + b_in_f[n]     (n < 256)
//                    = x[b,s,:] . W_in_b[:,n-256] + b_in_b[n-256] (n >= 256)
// M=64000, N=512, K=700. k-sequential FMA accumulation (order preserved).
// 128x128 tile, BK=16, 8x8 per thread in split-half fragments.
// Double-buffered LDS, register-staged global loads, ONE barrier per K-step:
//   [ds_write(buf) ; global->regs(next) ; barrier ; compute(buf)]
// Safety: writes in iter i+1 target buf^1 while any lagging wave's compute-i
// reads buf; all reads of buf_i precede barrier i+1 (program order: compute-i
// comes before iter-i+1's writes), and buf_i is only re-written after it.
// ---------------------------------------------------------------------------
#define BKK 16
#define APAD 132

__global__ __launch_bounds__(256) void proj_gemm(
    const float* __restrict__ x,
    const float* __restrict__ Wf,
    const float* __restrict__ Wb,
    const float* __restrict__ biasf,
    const float* __restrict__ biasb,
    float* __restrict__ P)
{
    __shared__ float As[2][BKK][APAD];  // [buf][k][m]
    __shared__ float Bs[2][BKK][128];   // [buf][k][n]

    const int nt = blockIdx.x;          // 0..3
    const int mt = blockIdx.y;          // 0..499
    const int m0 = mt * 128;
    const int n0 = nt * 128;
    const float* W   = (n0 < HID) ? Wf : Wb;
    const float* bia = (n0 < HID) ? biasf : biasb;
    const int wc0 = n0 & (HID - 1);     // 0 or 128 within selected W

    const int tid = threadIdx.x;
    const int tm = tid & 15, tn = tid >> 4;

    float acc[8][8];
#pragma unroll
    for (int i = 0; i < 8; i++)
#pragma unroll
        for (int j = 0; j < 8; j++) acc[i][j] = 0.f;

    // A staging map: thread -> (row ar+64*half, k-slot aq) float4 over k
    const int ar = tid >> 2;            // 0..63
    const int aq = tid & 3;             // k-slot (4 floats)
    // B staging map: thread -> (k-row bk+8*half, float4-slot bn)
    const int bn = tid & 31;            // 0..31
    const int bk = tid >> 5;            // 0..7

    float4 aR[2], bR[2];

    // prologue: stage tile k0=0 into registers
    {
        const int k0 = 0;
#pragma unroll
        for (int half = 0; half < 2; half++) {
            const int gka = k0 + aq * 4;
            aR[half] = make_float4(0.f, 0.f, 0.f, 0.f);
            if (gka < CIN)
                aR[half] = *(const float4*)&x[(size_t)(m0 + ar + half * 64) * CIN + gka];
            const int gkb = k0 + bk + half * 8;
            bR[half] = make_float4(0.f, 0.f, 0.f, 0.f);
            if (gkb < CIN)
                bR[half] = *(const float4*)&W[(size_t)gkb * HID + wc0 + bn * 4];
        }
    }

    int buf = 0;
    for (int k0 = 0; k0 < CIN; k0 += BKK) {
        // ---- write staged registers to LDS[buf]
#pragma unroll
        for (int half = 0; half < 2; half++) {
            const int r = ar + half * 64;
            As[buf][aq * 4 + 0][r] = aR[half].x;
            As[buf][aq * 4 + 1][r] = aR[half].y;
            As[buf][aq * 4 + 2][r] = aR[half].z;
            As[buf][aq * 4 + 3][r] = aR[half].w;
            *(float4*)&Bs[buf][bk + half * 8][bn * 4] = bR[half];
        }
        // ---- issue next tile's global loads (overlap barrier + compute)
        const int kn = k0 + BKK;
        if (kn < CIN) {
#pragma unroll
            for (int half = 0; half < 2; half++) {
                const int gka = kn + aq * 4;
                aR[half] = make_float4(0.f, 0.f, 0.f, 0.f);
                if (gka < CIN)
                    aR[half] = *(const float4*)&x[(size_t)(m0 + ar + half * 64) * CIN + gka];
                const int gkb = kn + bk + half * 8;
                bR[half] = make_float4(0.f, 0.f, 0.f, 0.f);
                if (gkb < CIN)
                    bR[half] = *(const float4*)&W[(size_t)gkb * HID + wc0 + bn * 4];
            }
        }
        __syncthreads();
        // ---- compute on LDS[buf]
#pragma unroll
        for (int kk = 0; kk < BKK; kk++) {
            const float4 a0 = *(const float4*)&As[buf][kk][tm * 4];
            const float4 a1 = *(const float4*)&As[buf][kk][64 + tm * 4];
            const float4 b0 = *(const float4*)&Bs[buf][kk][tn * 4];
            const float4 b1 = *(const float4*)&Bs[buf][kk][64 + tn * 4];
            const float av[8] = {a0.x, a0.y, a0.z, a0.w, a1.x, a1.y, a1.z, a1.w};
            const float bv[8] = {b0.x, b0.y, b0.z, b0.w, b1.x, b1.y, b1.z, b1.w};
#pragma unroll
            for (int i = 0; i < 8; i++)
#pragma unroll
                for (int j = 0; j < 8; j++)
                    acc[i][j] = __fmaf_rn(av[i], bv[j], acc[i][j]);
        }
        buf ^= 1;
    }

    float bb_[8];
#pragma unroll
    for (int j = 0; j < 8; j++)
        bb_[j] = bia[wc0 + (j >> 2) * 64 + tn * 4 + (j & 3)];
#pragma unroll
    for (int i = 0; i < 8; i++) {
        const int row = m0 + (i >> 2) * 64 + tm * 4 + (i & 3);
#pragma unroll
        for (int qj = 0; qj < 2; qj++) {
            float4 v;
            v.x = __fadd_rn(acc[i][qj * 4 + 0], bb_[qj * 4 + 0]);
            v.y = __fadd_rn(acc[i][qj * 4 + 1], bb_[qj * 4 + 1]);
            v.z = __fadd_rn(acc[i][qj * 4 + 2], bb_[qj * 4 + 2]);
            v.w = __fadd_rn(acc[i][qj * 4 + 3], bb_[qj * 4 + 3]);
            *(float4*)&P[(size_t)row * 512 + n0 + qj * 64 + tn * 4] = v;
        }
    }
}

// ---------------------------------------------------------------------------
// Kernel 2: sequential scan. One block per batch, 512 threads (tid<256 = fw
// neuron, tid>=256 = bw neuron). Spikes binary -> recurrent matmul is an
// ordered gather-sum of W_rec rows (bit-exact vs k-sequential fp32 GEMM).
// Gather is L2-latency-bound: 16-deep load batches for 16 outstanding loads.
// list[] stores column-local h (writer's tid&255) - no per-load subtract.
// Readout integrator is linear in spikes & feeds nothing back -> per-h leaky
// integrators in registers, one reduction at the end.
// ---------------------------------------------------------------------------
template<bool FUSED>
__global__ __launch_bounds__(512) void scan_kernel(
    const float* __restrict__ P,
    const float* __restrict__ x,
    const float* __restrict__ Winf, const float* __restrict__ binf,
    const float* __restrict__ Winb, const float* __restrict__ binb,
    const float* __restrict__ Wrecf, const float* __restrict__ brecf,
    const float* __restrict__ taumf, const float* __restrict__ tauaf,
    const float* __restrict__ Wrecb, const float* __restrict__ brecb,
    const float* __restrict__ taumb, const float* __restrict__ tauab,
    const float* __restrict__ Wout, const float* __restrict__ bout,
    const float* __restrict__ taumo,
    float* __restrict__ out)
{
    const int b   = blockIdx.x;
    const int tid = threadIdx.x;
    const int h   = tid & (HID - 1);
    const bool fw = tid < HID;
    const int lane = tid & 63;
    const int wv   = tid >> 6;          // wave 0..7

    __shared__ int pops[8];
    __shared__ int cnts[2][2];          // [buf][0]=cnt_fw, [1]=cnt_all
    __shared__ unsigned short list[2][512];
    __shared__ float part[8][OUT_N];
    __shared__ float memo_s[OUT_N];
    __shared__ float red2[2];
    __shared__ float xs[2][CIN];        // only used when FUSED

    if (tid < 2) { cnts[0][tid] = 0; }

    const float* Wrec = fw ? Wrecf : Wrecb;
    const float* Wcol = Wrec + h;
    const float brc   = fw ? brecf[h] : brecb[h];
    const float alpha = expf(__fdiv_rn(-1.f, fw ? taumf[h] : taumb[h]));
    const float ro    = expf(__fdiv_rn(-1.f, fw ? tauaf[h] : tauab[h]));
    const float omA   = __fsub_rn(1.f, alpha);
    const float omR   = __fsub_rn(1.f, ro);
    const float* Win  = fw ? Winf : Winb;
    const float* Wic  = Win + h;
    const float bi    = fw ? binf[h] : binb[h];

    // per-output leaky-integrator constants (register resident)
    float ao[OUT_N], omo[OUT_N], zacc[OUT_N];
#pragma unroll
    for (int o = 0; o < OUT_N; o++) {
        ao[o]   = expf(__fdiv_rn(-1.f, taumo[o]));
        omo[o]  = __fsub_rn(1.f, ao[o]);
        zacc[o] = 0.f;
    }

    float mem = 0.f, bbv = 0.01f, spk = 0.f;

    const unsigned long long below = (1ull << lane) - 1ull;

    __syncthreads();

    // prefetch step-0 projection
    float pv;
    if (!FUSED) {
        const int srow0 = fw ? 0 : (S_LEN - 1);
        pv = P[((size_t)b * S_LEN + srow0) * 512 + tid];
    }

    for (int s = 0; s < S_LEN; s++) {
        const int rbuf = s & 1, wbuf = rbuf ^ 1;

        float pv_next = 0.f;
        if (!FUSED) {
            const int sn   = (s + 1 < S_LEN) ? s + 1 : S_LEN - 1;
            const int srow = fw ? sn : (S_LEN - 1 - sn);
            pv_next = P[((size_t)b * S_LEN + srow) * 512 + tid];
        } else {
            const float* xrf = x + ((size_t)b * S_LEN + s) * CIN;
            const float* xrb = x + ((size_t)b * S_LEN + (S_LEN - 1 - s)) * CIN;
            for (int c = tid; c < CIN; c += 512) {
                xs[0][c] = xrf[c];
                xs[1][c] = xrb[c];
            }
            __syncthreads();
            const float* xr = fw ? xs[0] : xs[1];
            float a0 = 0.f;
            for (int c = 0; c < CIN; c += 4) {
                float w0 = Wic[(size_t)(c + 0) * HID];
                float w1 = Wic[(size_t)(c + 1) * HID];
                float w2 = Wic[(size_t)(c + 2) * HID];
                float w3 = Wic[(size_t)(c + 3) * HID];
                a0 = __fmaf_rn(xr[c + 0], w0, a0);
                a0 = __fmaf_rn(xr[c + 1], w1, a0);
                a0 = __fmaf_rn(xr[c + 2], w2, a0);
                a0 = __fmaf_rn(xr[c + 3], w3, a0);
            }
            pv = __fadd_rn(a0, bi);
        }

        // ---- recurrent gather: ordered sum of W_rec rows for spiking h'
        const int cf = cnts[rbuf][0], ca = cnts[rbuf][1];
        const int i0 = fw ? 0 : cf;
        const int i1 = fw ? cf : ca;
        const unsigned short* lst = list[rbuf];
        float acc = 0.f;
        {
            int i = i0;
            for (; i + 16 <= i1; i += 16) {
                float w[16];
#pragma unroll
                for (int u = 0; u < 16; u++)
                    w[u] = Wcol[(int)lst[i + u] << 8];
#pragma unroll
                for (int u = 0; u < 16; u++) acc = __fadd_rn(acc, w[u]);
            }
            if (i + 8 <= i1) {
                float w[8];
#pragma unroll
                for (int u = 0; u < 8; u++)
                    w[u] = Wcol[(int)lst[i + u] << 8];
#pragma unroll
                for (int u = 0; u < 8; u++) acc = __fadd_rn(acc, w[u]);
                i += 8;
            }
            for (; i < i1; i++)
                acc = __fadd_rn(acc, Wcol[(int)lst[i] << 8]);
        }

        // ---- adaptive-LIF state update (rounding order matches reference)
        const float d  = __fadd_rn(__fadd_rn(pv, acc), brc);
        bbv = __fadd_rn(__fmul_rn(ro, bbv), __fmul_rn(omR, spk));
        const float thr = __fadd_rn(0.01f, __fmul_rn(1.8f, bbv));
        mem = __fsub_rn(__fadd_rn(__fmul_rn(mem, alpha), __fmul_rn(omA, d)),
                        __fmul_rn(thr, spk));
        const bool sp = __fsub_rn(mem, thr) > 0.f;
        spk = sp ? 1.f : 0.f;

        const unsigned long long bal = __ballot(sp);
        if (lane == 0) pops[wv] = __popcll(bal);
        __syncthreads();   // A: pops(t) visible

        // parallel rank-based sorted list build (ascending tid order);
        // store column-local index h (gatherers only read their own half)
        {
            int off = 0;
#pragma unroll
            for (int w2 = 0; w2 < 7; w2++)
                if (w2 < wv) off += pops[w2];
            if (sp) {
                off += __popcll(bal & below);
                list[wbuf][off] = (unsigned short)h;
            }
        }
        if (tid == 0) {
            const int c0 = pops[0] + pops[1] + pops[2] + pops[3];
            cnts[wbuf][0] = c0;
            cnts[wbuf][1] = c0 + pops[4] + pops[5] + pops[6] + pops[7];
        }

        // ---- readout: per-h leaky integrator (linear, no feedback)
        const float sv = spk;
#pragma unroll
        for (int o = 0; o < OUT_N; o++)
            zacc[o] = __fmaf_rn(ao[o], zacc[o], __fmul_rn(omo[o], sv));

        if (!FUSED) pv = pv_next;
        __syncthreads();   // B: list(t), cnts(t) visible
    }

    // ---- final readout reduction: mem_o[o] = sum_h zacc_h[o]*W_out[h][o]
    //                                          + b_o*(1 - alpha_o^S)
#pragma unroll
    for (int o = 0; o < OUT_N; o++) {
        float v = __fmul_rn(zacc[o], Wout[(size_t)tid * OUT_N + o]);
#pragma unroll
        for (int d2 = 1; d2 < 64; d2 <<= 1)
            v += __shfl_xor(v, d2, 64);
        if (lane == 0) part[wv][o] = v;
    }
    __syncthreads();
    if (tid < OUT_N) {
        float tot = part[0][tid];
#pragma unroll
        for (int w2 = 1; w2 < 8; w2++) tot = __fadd_rn(tot, part[w2][tid]);
        const float aS = expf(__fdiv_rn(-(float)S_LEN, taumo[tid]));
        tot = __fadd_rn(tot, __fmul_rn(bout[tid], __fsub_rn(1.f, aS)));
        memo_s[tid] = tot;
    }
    __syncthreads();
    if (tid == 0) {
        float mx = memo_s[0];
        for (int o = 1; o < OUT_N; o++) mx = fmaxf(mx, memo_s[o]);
        float se = 0.f;
        for (int o = 0; o < OUT_N; o++) se += expf(__fsub_rn(memo_s[o], mx));
        red2[0] = mx;
        red2[1] = logf(se);
    }
    __syncthreads();
    if (tid < OUT_N)
        out[(size_t)b * OUT_N + tid] =
            __fsub_rn(__fsub_rn(memo_s[tid], red2[0]), red2[1]);
}

// ---------------------------------------------------------------------------
extern "C" void kernel_launch(void* const* d_in, const int* in_sizes, int n_in,
                              void* d_out, int out_size, void* d_ws, size_t ws_size,
                              hipStream_t stream) {
    const float* x         = (const float*)d_in[0];
    const float* W_in_f    = (const float*)d_in[1];
    const float* b_in_f    = (const float*)d_in[2];
    const float* W_rec_f   = (const float*)d_in[3];
    const float* b_rec_f   = (const float*)d_in[4];
    const float* tau_m_f   = (const float*)d_in[5];
    const float* tau_adp_f = (const float*)d_in[6];
    const float* W_in_b    = (const float*)d_in[7];
    const float* b_in_b    = (const float*)d_in[8];
    const float* W_rec_b   = (const float*)d_in[9];
    const float* b_rec_b   = (const float*)d_in[10];
    const float* tau_m_b   = (const float*)d_in[11];
    const float* tau_adp_b = (const float*)d_in[12];
    const float* W_out     = (const float*)d_in[13];
    const float* b_out     = (const float*)d_in[14];
    const float* tau_m_o   = (const float*)d_in[15];
    float* out = (float*)d_out;
    float* P   = (float*)d_ws;

    const size_t needP = (size_t)BATCH * S_LEN * 512 * sizeof(float);
    const bool fused = (d_ws == nullptr) || (ws_size < needP);

    if (!fused) {
        proj_gemm<<<dim3(4, 500), dim3(256), 0, stream>>>(
            x, W_in_f, W_in_b, b_in_f, b_in_b, P);
        scan_kernel<false><<<dim3(BATCH), dim3(512), 0, stream>>>(
            P, x, W_in_f, b_in_f, W_in_b, b_in_b,
            W_rec_f, b_rec_f, tau_m_f, tau_adp_f,
            W_rec_b, b_rec_b, tau_m_b, tau_adp_b,
            W_out, b_out, tau_m_o, out);
    } else {
        scan_kernel<true><<<dim3(BATCH), dim3(512), 0, stream>>>(
            nullptr, x, W_in_f, b_in_f, W_in_b, b_in_b,
            W_rec_f, b_rec_f, tau_m_f, tau_adp_f,
            W_rec_b, b_rec_b, tau_m_b, tau_adp_b,
            W_out, b_out, tau_m_o, out);
    }
}

// Round 4
// 576.584 us; speedup vs baseline: 2.8271x; 1.5616x over previous
//
#include <hip/hip_runtime.h>
#include <cstdint>
#include <cstddef>

#define S_LEN 250
#define BATCH 256
#define CIN   700
#define HID   256
#define OUT_N 20
#define KSTEPS 22   // ceil(700/32)

typedef __attribute__((ext_vector_type(8))) short bf16x8;
typedef __attribute__((ext_vector_type(4))) float f32x4;

__device__ __forceinline__ ushort f2bf_rne(float f) {
    uint u = __float_as_uint(f);
    uint r = (u + 0x7FFFu + ((u >> 16) & 1u)) >> 16;
    return (ushort)r;
}
__device__ __forceinline__ float bf2f(ushort h) {
    return __uint_as_float(((uint)h) << 16);
}

// ---------------------------------------------------------------------------
// Kernel 1: input projection GEMM via bf16x3 split MFMA.
// P[(b*S+s)*512 + n] = x[b,s,:] . W[:,n'] + bias[n'].
// Each fp32 a = a_hi + a_lo (bf16 RNE split, 16 effective mantissa bits).
// a*b ~= aH*bH + aH*bL + aL*bH accumulated in fp32 MFMA accs: per-product
// rel err ~2^-17 -> pv abs err ~1.5e-6, same class as fp32 reorder noise.
// Tile 128x128, K-step 32, 4 waves (2x2 of 64x64), 16x16x32 bf16 MFMA,
// 4x4 frags/wave. LDS: 4 planes [128][40] ushort (80B pitch: 16B-aligned
// rows, 2-way-max bank pattern on b128 frag reads) = 40KB -> 3 blocks/CU.
// Global loads issued before barrier 1 -> overlap previous MFMA phase.
// ---------------------------------------------------------------------------
__global__ __launch_bounds__(256) void proj_mfma(
    const float* __restrict__ x,
    const float* __restrict__ Wf, const float* __restrict__ Wb,
    const float* __restrict__ biasf, const float* __restrict__ biasb,
    float* __restrict__ P)
{
    __shared__ ushort AsH[128][40];
    __shared__ ushort AsL[128][40];
    __shared__ ushort BsH[128][40];
    __shared__ ushort BsL[128][40];

    const int nt = blockIdx.x;          // 0..3 (n-tile)
    const int mt = blockIdx.y;          // 0..499
    const int m0 = mt * 128;
    const float* W   = (nt < 2) ? Wf : Wb;
    const float* bia = (nt < 2) ? biasf : biasb;
    const int wc0 = (nt & 1) * 128;

    const int tid  = threadIdx.x;
    const int lane = tid & 63;
    const int wv   = tid >> 6;          // wave 0..3
    const int wr   = wv >> 1;           // wave row 0..1 (64 rows each)
    const int wc   = wv & 1;            // wave col 0..1
    const int l15  = lane & 15;
    const int l4   = lane >> 4;

    // A staging: thread -> k-quad (as), rows arr+32*i
    const int as  = tid & 7;
    const int arr = tid >> 3;           // 0..31
    // B staging: thread -> col bcol, k-half bkh (16 k each)
    const int bcol = tid & 127;
    const int bkh  = tid >> 7;          // 0..1

    f32x4 acc[4][4];
#pragma unroll
    for (int i = 0; i < 4; i++)
#pragma unroll
        for (int j = 0; j < 4; j++)
            acc[i][j] = (f32x4){0.f, 0.f, 0.f, 0.f};

    for (int kt = 0; kt < KSTEPS; kt++) {
        const int k0 = kt * 32;

        // ---- global loads (regs only; overlap previous compute phase)
        float4 av[4];
        const int ka = k0 + as * 4;
        const bool aok = (ka + 3) < CIN;     // CIN%4==0: quad all-or-none
#pragma unroll
        for (int i = 0; i < 4; i++) {
            av[i] = make_float4(0.f, 0.f, 0.f, 0.f);
            if (aok)
                av[i] = *(const float4*)&x[(size_t)(m0 + arr + 32 * i) * CIN + ka];
        }
        float bv[16];
#pragma unroll
        for (int j = 0; j < 16; j++) {
            const int kb = k0 + bkh * 16 + j;
            bv[j] = (kb < CIN) ? W[(size_t)kb * HID + wc0 + bcol] : 0.f;
        }

        __syncthreads();   // prior compute done -> LDS reusable

        // ---- convert + LDS write
#pragma unroll
        for (int i = 0; i < 4; i++) {
            const int row = arr + 32 * i;
            ushort4 h, l;
            h.x = f2bf_rne(av[i].x); l.x = f2bf_rne(__fsub_rn(av[i].x, bf2f(h.x)));
            h.y = f2bf_rne(av[i].y); l.y = f2bf_rne(__fsub_rn(av[i].y, bf2f(h.y)));
            h.z = f2bf_rne(av[i].z); l.z = f2bf_rne(__fsub_rn(av[i].z, bf2f(h.z)));
            h.w = f2bf_rne(av[i].w); l.w = f2bf_rne(__fsub_rn(av[i].w, bf2f(h.w)));
            *(ushort4*)&AsH[row][as * 4] = h;
            *(ushort4*)&AsL[row][as * 4] = l;
        }
#pragma unroll
        for (int q = 0; q < 4; q++) {
            ushort4 h, l;
            float v0 = bv[q * 4 + 0], v1 = bv[q * 4 + 1];
            float v2 = bv[q * 4 + 2], v3 = bv[q * 4 + 3];
            h.x = f2bf_rne(v0); l.x = f2bf_rne(__fsub_rn(v0, bf2f(h.x)));
            h.y = f2bf_rne(v1); l.y = f2bf_rne(__fsub_rn(v1, bf2f(h.y)));
            h.z = f2bf_rne(v2); l.z = f2bf_rne(__fsub_rn(v2, bf2f(h.z)));
            h.w = f2bf_rne(v3); l.w = f2bf_rne(__fsub_rn(v3, bf2f(h.w)));
            *(ushort4*)&BsH[bcol][bkh * 16 + q * 4] = h;
            *(ushort4*)&BsL[bcol][bkh * 16 + q * 4] = l;
        }
        __syncthreads();   // LDS ready

        // ---- fragment reads (ds_read_b128)
        bf16x8 aH[4], aL[4], bH[4], bL[4];
#pragma unroll
        for (int f = 0; f < 4; f++) {
            aH[f] = *(const bf16x8*)&AsH[wr * 64 + f * 16 + l15][l4 * 8];
            aL[f] = *(const bf16x8*)&AsL[wr * 64 + f * 16 + l15][l4 * 8];
            bH[f] = *(const bf16x8*)&BsH[wc * 64 + f * 16 + l15][l4 * 8];
            bL[f] = *(const bf16x8*)&BsL[wc * 64 + f * 16 + l15][l4 * 8];
        }
        // ---- 3-term split MFMA: hh (dominant) then cross terms
#pragma unroll
        for (int fr = 0; fr < 4; fr++)
#pragma unroll
            for (int fc = 0; fc < 4; fc++) {
                acc[fr][fc] = __builtin_amdgcn_mfma_f32_16x16x32_bf16(
                    aH[fr], bH[fc], acc[fr][fc], 0, 0, 0);
                acc[fr][fc] = __builtin_amdgcn_mfma_f32_16x16x32_bf16(
                    aH[fr], bL[fc], acc[fr][fc], 0, 0, 0);
                acc[fr][fc] = __builtin_amdgcn_mfma_f32_16x16x32_bf16(
                    aL[fr], bH[fc], acc[fr][fc], 0, 0, 0);
            }
    }

    // ---- epilogue: bias add + store (D layout: col=lane&15, row=(lane>>4)*4+j)
#pragma unroll
    for (int fc = 0; fc < 4; fc++) {
        const float bvs = bia[wc0 + wc * 64 + fc * 16 + l15];
#pragma unroll
        for (int fr = 0; fr < 4; fr++) {
#pragma unroll
            for (int j = 0; j < 4; j++) {
                const int row = m0 + wr * 64 + fr * 16 + l4 * 4 + j;
                P[(size_t)row * 512 + nt * 128 + wc * 64 + fc * 16 + l15] =
                    __fadd_rn(acc[fr][fc][j], bvs);
            }
        }
    }
}

// ---------------------------------------------------------------------------
// Kernel 2: sequential scan, SPLIT per direction: grid (256 batches, 2 halves),
// 256 threads (= one neuron each). fw and bw chains are independent (coupling
// is only the linear readout, kept as per-thread integrators). 2 blocks/CU
// hide each other's gather latency; 4-wave barriers are cheap.
// Spikes binary -> recurrent matmul = ordered gather-sum of W_rec rows
// (bit-exact vs k-sequential fp32 GEMM). Partial readouts are written into
// the already-consumed P region (row b*250, cols half*256+0..19: disjoint
// from every remaining read of the other half).
// ---------------------------------------------------------------------------
__global__ __launch_bounds__(256) void scan_half(
    const float* __restrict__ P,
    const float* __restrict__ Wrecf, const float* __restrict__ brecf,
    const float* __restrict__ taumf, const float* __restrict__ tauaf,
    const float* __restrict__ Wrecb, const float* __restrict__ brecb,
    const float* __restrict__ taumb, const float* __restrict__ tauab,
    const float* __restrict__ Wout, const float* __restrict__ taumo,
    float* __restrict__ Ppart)
{
    const int b    = blockIdx.x;
    const int half = blockIdx.y;        // 0 = fw, 1 = bw
    const int tid  = threadIdx.x;       // neuron h
    const int lane = tid & 63;
    const int wv   = tid >> 6;          // wave 0..3

    __shared__ int pops[2][4];
    __shared__ unsigned short list[2][HID];
    __shared__ float part[4][OUT_N];

    if (tid < 4) pops[0][tid] = 0;

    const bool fw = (half == 0);
    const float* Wrec = fw ? Wrecf : Wrecb;
    const float* Wcol = Wrec + tid;
    const float brc   = fw ? brecf[tid] : brecb[tid];
    const float alpha = expf(__fdiv_rn(-1.f, fw ? taumf[tid] : taumb[tid]));
    const float ro    = expf(__fdiv_rn(-1.f, fw ? tauaf[tid] : tauab[tid]));
    const float omA   = __fsub_rn(1.f, alpha);
    const float omR   = __fsub_rn(1.f, ro);

    float ao[OUT_N], omo[OUT_N], zacc[OUT_N];
#pragma unroll
    for (int o = 0; o < OUT_N; o++) {
        ao[o]   = expf(__fdiv_rn(-1.f, taumo[o]));
        omo[o]  = __fsub_rn(1.f, ao[o]);
        zacc[o] = 0.f;
    }

    float mem = 0.f, bbv = 0.01f, spk = 0.f;
    const unsigned long long below = (1ull << lane) - 1ull;

    __syncthreads();   // publish pops[0] zeros

    float pv = P[((size_t)b * S_LEN + (fw ? 0 : S_LEN - 1)) * 512 + half * HID + tid];

    for (int s = 0; s < S_LEN; s++) {
        const int rbuf = s & 1, wbuf = rbuf ^ 1;

        const int sn   = (s + 1 < S_LEN) ? s + 1 : S_LEN - 1;
        const int srow = fw ? sn : (S_LEN - 1 - sn);
        const float pv_next =
            P[((size_t)b * S_LEN + srow) * 512 + half * HID + tid];

        // ---- recurrent gather: ordered sum of W_rec rows for spiking h'
        const int cnt = pops[rbuf][0] + pops[rbuf][1] + pops[rbuf][2] + pops[rbuf][3];
        const unsigned short* lst = list[rbuf];
        float acc = 0.f;
        {
            int i = 0;
            for (; i + 16 <= cnt; i += 16) {
                float w[16];
#pragma unroll
                for (int u = 0; u < 16; u++)
                    w[u] = Wcol[(int)lst[i + u] << 8];
#pragma unroll
                for (int u = 0; u < 16; u++) acc = __fadd_rn(acc, w[u]);
            }
            if (i + 8 <= cnt) {
                float w[8];
#pragma unroll
                for (int u = 0; u < 8; u++)
                    w[u] = Wcol[(int)lst[i + u] << 8];
#pragma unroll
                for (int u = 0; u < 8; u++) acc = __fadd_rn(acc, w[u]);
                i += 8;
            }
            for (; i < cnt; i++)
                acc = __fadd_rn(acc, Wcol[(int)lst[i] << 8]);
        }

        // ---- adaptive-LIF update (rounding order matches reference)
        const float d  = __fadd_rn(__fadd_rn(pv, acc), brc);
        bbv = __fadd_rn(__fmul_rn(ro, bbv), __fmul_rn(omR, spk));
        const float thr = __fadd_rn(0.01f, __fmul_rn(1.8f, bbv));
        mem = __fsub_rn(__fadd_rn(__fmul_rn(mem, alpha), __fmul_rn(omA, d)),
                        __fmul_rn(thr, spk));
        const bool sp = __fsub_rn(mem, thr) > 0.f;
        spk = sp ? 1.f : 0.f;

        const unsigned long long bal = __ballot(sp);
        if (lane == 0) pops[wbuf][wv] = __popcll(bal);
        __syncthreads();   // A: pops(t) visible

        // rank-based sorted list build (ascending h order)
        {
            int off = 0;
#pragma unroll
            for (int w2 = 0; w2 < 3; w2++)
                if (w2 < wv) off += pops[wbuf][w2];
            if (sp) {
                off += __popcll(bal & below);
                list[wbuf][off] = (unsigned short)tid;
            }
        }

        // ---- readout: per-neuron leaky integrator (linear, no feedback)
        const float sv = spk;
#pragma unroll
        for (int o = 0; o < OUT_N; o++)
            zacc[o] = __fmaf_rn(ao[o], zacc[o], __fmul_rn(omo[o], sv));

        pv = pv_next;
        __syncthreads();   // B: list(t) published
    }

    // ---- half-partial: part[o] = sum_h zacc_h[o] * Wout[half*256+h][o]
#pragma unroll
    for (int o = 0; o < OUT_N; o++) {
        float v = __fmul_rn(zacc[o], Wout[(size_t)(half * HID + tid) * OUT_N + o]);
#pragma unroll
        for (int d2 = 1; d2 < 64; d2 <<= 1)
            v += __shfl_xor(v, d2, 64);
        if (lane == 0) part[wv][o] = v;
    }
    __syncthreads();
    if (tid < OUT_N) {
        float tot = __fadd_rn(__fadd_rn(part[0][tid], part[1][tid]),
                              __fadd_rn(part[2][tid], part[3][tid]));
        // stash in consumed P region: row b*250, col half*256 + o
        Ppart[(size_t)b * S_LEN * 512 + half * HID + tid] = tot;
    }
}

// ---------------------------------------------------------------------------
// Kernel 3: merge fw/bw partials + bias term + log_softmax. One block/batch.
// mem_o = pf + pb + b_o*(1 - alpha_o^S)   (readout integrator linearity)
// ---------------------------------------------------------------------------
__global__ __launch_bounds__(64) void merge_out(
    const float* __restrict__ Pp, const float* __restrict__ bout,
    const float* __restrict__ taumo, float* __restrict__ out)
{
    const int b = blockIdx.x;
    const int o = threadIdx.x;          // 0..63, active 0..19

    float val = 0.f, v = -3.0e38f;
    if (o < OUT_N) {
        const float pf = Pp[(size_t)b * S_LEN * 512 + o];
        const float pb = Pp[(size_t)b * S_LEN * 512 + HID + o];
        const float aS = expf(__fdiv_rn(-(float)S_LEN, taumo[o]));
        val = __fadd_rn(__fadd_rn(pf, pb),
                        __fmul_rn(bout[o], __fsub_rn(1.f, aS)));
        v = val;
    }
    float mx = v;
#pragma unroll
    for (int d2 = 1; d2 < 64; d2 <<= 1)
        mx = fmaxf(mx, __shfl_xor(mx, d2, 64));
    float e = (o < OUT_N) ? expf(__fsub_rn(val, mx)) : 0.f;
#pragma unroll
    for (int d2 = 1; d2 < 64; d2 <<= 1)
        e += __shfl_xor(e, d2, 64);
    if (o < OUT_N)
        out[(size_t)b * OUT_N + o] =
            __fsub_rn(__fsub_rn(val, mx), logf(e));
}

// ---------------------------------------------------------------------------
extern "C" void kernel_launch(void* const* d_in, const int* in_sizes, int n_in,
                              void* d_out, int out_size, void* d_ws, size_t ws_size,
                              hipStream_t stream) {
    const float* x         = (const float*)d_in[0];
    const float* W_in_f    = (const float*)d_in[1];
    const float* b_in_f    = (const float*)d_in[2];
    const float* W_rec_f   = (const float*)d_in[3];
    const float* b_rec_f   = (const float*)d_in[4];
    const float* tau_m_f   = (const float*)d_in[5];
    const float* tau_adp_f = (const float*)d_in[6];
    const float* W_in_b    = (const float*)d_in[7];
    const float* b_in_b    = (const float*)d_in[8];
    const float* W_rec_b   = (const float*)d_in[9];
    const float* b_rec_b   = (const float*)d_in[10];
    const float* tau_m_b   = (const float*)d_in[11];
    const float* tau_adp_b = (const float*)d_in[12];
    const float* W_out     = (const float*)d_in[13];
    const float* b_out     = (const float*)d_in[14];
    const float* tau_m_o   = (const float*)d_in[15];
    float* out = (float*)d_out;
    float* P   = (float*)d_ws;

    // ws_size proven >= 131.07MB on this harness (proj path ran rounds 1-3)
    proj_mfma<<<dim3(4, 500), dim3(256), 0, stream>>>(
        x, W_in_f, W_in_b, b_in_f, b_in_b, P);
    scan_half<<<dim3(BATCH, 2), dim3(256), 0, stream>>>(
        P, W_rec_f, b_rec_f, tau_m_f, tau_adp_f,
        W_rec_b, b_rec_b, tau_m_b, tau_adp_b,
        W_out, tau_m_o, P);
    merge_out<<<dim3(BATCH), dim3(64), 0, stream>>>(
        P, b_out, tau_m_o, out);
}

// Round 6
// 517.688 us; speedup vs baseline: 3.1487x; 1.1138x over previous
//
#include <hip/hip_runtime.h>
#include <cstdint>
#include <cstddef>

#define S_LEN 250
#define BATCH 256
#define CIN   700
#define HID   256
#define OUT_N 20
#define KSTEPS 22   // ceil(700/32)

typedef __attribute__((ext_vector_type(8))) short bf16x8;
typedef __attribute__((ext_vector_type(4))) float f32x4;

__device__ __forceinline__ ushort f2bf_rne(float f) {
    uint u = __float_as_uint(f);
    uint r = (u + 0x7FFFu + ((u >> 16) & 1u)) >> 16;
    return (ushort)r;
}
__device__ __forceinline__ float bf2f(ushort h) {
    return __uint_as_float(((uint)h) << 16);
}

// ---------------------------------------------------------------------------
// Kernel 1: input projection GEMM via bf16x3 split MFMA (unchanged from R3:
// verified layouts, absmax unchanged vs fp32 path).
// ---------------------------------------------------------------------------
__global__ __launch_bounds__(256) void proj_mfma(
    const float* __restrict__ x,
    const float* __restrict__ Wf, const float* __restrict__ Wb,
    const float* __restrict__ biasf, const float* __restrict__ biasb,
    float* __restrict__ P)
{
    __shared__ ushort AsH[128][40];
    __shared__ ushort AsL[128][40];
    __shared__ ushort BsH[128][40];
    __shared__ ushort BsL[128][40];

    const int nt = blockIdx.x;
    const int mt = blockIdx.y;
    const int m0 = mt * 128;
    const float* W   = (nt < 2) ? Wf : Wb;
    const float* bia = (nt < 2) ? biasf : biasb;
    const int wc0 = (nt & 1) * 128;

    const int tid  = threadIdx.x;
    const int lane = tid & 63;
    const int wv   = tid >> 6;
    const int wr   = wv >> 1;
    const int wc   = wv & 1;
    const int l15  = lane & 15;
    const int l4   = lane >> 4;

    const int as  = tid & 7;
    const int arr = tid >> 3;
    const int bcol = tid & 127;
    const int bkh  = tid >> 7;

    f32x4 acc[4][4];
#pragma unroll
    for (int i = 0; i < 4; i++)
#pragma unroll
        for (int j = 0; j < 4; j++)
            acc[i][j] = (f32x4){0.f, 0.f, 0.f, 0.f};

    for (int kt = 0; kt < KSTEPS; kt++) {
        const int k0 = kt * 32;

        float4 av[4];
        const int ka = k0 + as * 4;
        const bool aok = (ka + 3) < CIN;
#pragma unroll
        for (int i = 0; i < 4; i++) {
            av[i] = make_float4(0.f, 0.f, 0.f, 0.f);
            if (aok)
                av[i] = *(const float4*)&x[(size_t)(m0 + arr + 32 * i) * CIN + ka];
        }
        float bv[16];
#pragma unroll
        for (int j = 0; j < 16; j++) {
            const int kb = k0 + bkh * 16 + j;
            bv[j] = (kb < CIN) ? W[(size_t)kb * HID + wc0 + bcol] : 0.f;
        }

        __syncthreads();

#pragma unroll
        for (int i = 0; i < 4; i++) {
            const int row = arr + 32 * i;
            ushort4 h, l;
            h.x = f2bf_rne(av[i].x); l.x = f2bf_rne(__fsub_rn(av[i].x, bf2f(h.x)));
            h.y = f2bf_rne(av[i].y); l.y = f2bf_rne(__fsub_rn(av[i].y, bf2f(h.y)));
            h.z = f2bf_rne(av[i].z); l.z = f2bf_rne(__fsub_rn(av[i].z, bf2f(h.z)));
            h.w = f2bf_rne(av[i].w); l.w = f2bf_rne(__fsub_rn(av[i].w, bf2f(h.w)));
            *(ushort4*)&AsH[row][as * 4] = h;
            *(ushort4*)&AsL[row][as * 4] = l;
        }
#pragma unroll
        for (int q = 0; q < 4; q++) {
            ushort4 h, l;
            float v0 = bv[q * 4 + 0], v1 = bv[q * 4 + 1];
            float v2 = bv[q * 4 + 2], v3 = bv[q * 4 + 3];
            h.x = f2bf_rne(v0); l.x = f2bf_rne(__fsub_rn(v0, bf2f(h.x)));
            h.y = f2bf_rne(v1); l.y = f2bf_rne(__fsub_rn(v1, bf2f(h.y)));
            h.z = f2bf_rne(v2); l.z = f2bf_rne(__fsub_rn(v2, bf2f(h.z)));
            h.w = f2bf_rne(v3); l.w = f2bf_rne(__fsub_rn(v3, bf2f(h.w)));
            *(ushort4*)&BsH[bcol][bkh * 16 + q * 4] = h;
            *(ushort4*)&BsL[bcol][bkh * 16 + q * 4] = l;
        }
        __syncthreads();

        bf16x8 aH[4], aL[4], bH[4], bL[4];
#pragma unroll
        for (int f = 0; f < 4; f++) {
            aH[f] = *(const bf16x8*)&AsH[wr * 64 + f * 16 + l15][l4 * 8];
            aL[f] = *(const bf16x8*)&AsL[wr * 64 + f * 16 + l15][l4 * 8];
            bH[f] = *(const bf16x8*)&BsH[wc * 64 + f * 16 + l15][l4 * 8];
            bL[f] = *(const bf16x8*)&BsL[wc * 64 + f * 16 + l15][l4 * 8];
        }
#pragma unroll
        for (int fr = 0; fr < 4; fr++)
#pragma unroll
            for (int fc = 0; fc < 4; fc++) {
                acc[fr][fc] = __builtin_amdgcn_mfma_f32_16x16x32_bf16(
                    aH[fr], bH[fc], acc[fr][fc], 0, 0, 0);
                acc[fr][fc] = __builtin_amdgcn_mfma_f32_16x16x32_bf16(
                    aH[fr], bL[fc], acc[fr][fc], 0, 0, 0);
                acc[fr][fc] = __builtin_amdgcn_mfma_f32_16x16x32_bf16(
                    aL[fr], bH[fc], acc[fr][fc], 0, 0, 0);
            }
    }

#pragma unroll
    for (int fc = 0; fc < 4; fc++) {
        const float bvs = bia[wc0 + wc * 64 + fc * 16 + l15];
#pragma unroll
        for (int fr = 0; fr < 4; fr++) {
#pragma unroll
            for (int j = 0; j < 4; j++) {
                const int row = m0 + wr * 64 + fr * 16 + l4 * 4 + j;
                P[(size_t)row * 512 + nt * 128 + wc * 64 + fc * 16 + l15] =
                    __fadd_rn(acc[fr][fc][j], bvs);
            }
        }
    }
}

// ---------------------------------------------------------------------------
// Kernel 2: MFMA scan. Block = (direction, group of 16 batches); 512 threads
// = 8 waves; wave w owns output cols [w*32, w*32+32). W_rec is split hi+lo
// bf16 and held ENTIRELY in VGPRs (spikes are 0/1 -> MFMA products exact;
// residual 2^-17 per weight, ~2.5e-7/step on mem: below the perturbation
// already shown harmless in R4). Per step: one barrier; 8 A-frag LDS reads;
// 32 recurrent MFMA + 4 readout MFMA; per-thread LIF on the C/D fragment
// (row=batch=(lane>>4)*4+j, col=lane&15 within tile). Spikes exchanged via
// double-buffered LDS tile (pitch 264: conflict-minimal b128 reads).
// Readout handled by per-wave MFMA partial integrators (linearity), stashed
// into consumed P rows (rows b0*250+0..9, own direction's column half).
// ---------------------------------------------------------------------------
__global__ __launch_bounds__(512, 2) void scan_mfma(
    const float* __restrict__ P,
    const float* __restrict__ Wrecf, const float* __restrict__ brecf,
    const float* __restrict__ taumf, const float* __restrict__ tauaf,
    const float* __restrict__ Wrecb, const float* __restrict__ brecb,
    const float* __restrict__ taumb, const float* __restrict__ tauab,
    const float* __restrict__ Wout, const float* __restrict__ taumo,
    float* __restrict__ Pst)
{
    const int g  = blockIdx.x;          // batch group: b0..b0+15
    const int d  = blockIdx.y;          // 0 = fw, 1 = bw
    const int b0 = g * 16;
    const bool fw = (d == 0);

    const int tid  = threadIdx.x;
    const int lane = tid & 63;
    const int w    = tid >> 6;          // wave 0..7
    const int l15  = lane & 15;
    const int l4   = lane >> 4;

    __shared__ ushort Sp[2][16][264];   // [buf][batch][col(+pad)] bf16 spikes

    {   // zero both spike buffers (step -1 spikes = 0)
        ushort* p = &Sp[0][0][0];
        for (int i = tid; i < 2 * 16 * 264; i += 512) p[i] = 0;
    }

    const float* Wrec = fw ? Wrecf : Wrecb;

    // ---- W_rec fragments (hi+lo bf16), register resident: 128 VGPR
    bf16x8 whf[8][2], wlf[8][2];
#pragma unroll
    for (int kt = 0; kt < 8; kt++)
#pragma unroll
        for (int ct = 0; ct < 2; ct++) {
            const int c = w * 32 + ct * 16 + l15;
#pragma unroll
            for (int j = 0; j < 8; j++) {
                const float v = Wrec[(size_t)(kt * 32 + l4 * 8 + j) * HID + c];
                const ushort h = f2bf_rne(v);
                const ushort l = f2bf_rne(__fsub_rn(v, bf2f(h)));
                whf[kt][ct][j] = (short)h;
                wlf[kt][ct][j] = (short)l;
            }
        }

    // ---- W_out fragments for this wave's 32-k slice (hi+lo)
    bf16x8 woh[2], wol[2];
#pragma unroll
    for (int t = 0; t < 2; t++) {
        const int o = t * 16 + l15;
#pragma unroll
        for (int j = 0; j < 8; j++) {
            float v = 0.f;
            if (o < OUT_N)
                v = Wout[(size_t)(d * HID + w * 32 + l4 * 8 + j) * OUT_N + o];
            const ushort h = f2bf_rne(v);
            const ushort l = f2bf_rne(__fsub_rn(v, bf2f(h)));
            woh[t][j] = (short)h;
            wol[t][j] = (short)l;
        }
    }

    // ---- LIF constants for this thread's 2 columns
    float alpha_[2], ro_[2], omA_[2], omR_[2], brc_[2];
#pragma unroll
    for (int t = 0; t < 2; t++) {
        const int c = w * 32 + t * 16 + l15;
        alpha_[t] = expf(__fdiv_rn(-1.f, fw ? taumf[c] : taumb[c]));
        ro_[t]    = expf(__fdiv_rn(-1.f, fw ? tauaf[c] : tauab[c]));
        omA_[t]   = __fsub_rn(1.f, alpha_[t]);
        omR_[t]   = __fsub_rn(1.f, ro_[t]);
        brc_[t]   = fw ? brecf[c] : brecb[c];
    }
    // ---- readout constants for this thread's 2 output columns
    float ao_[2], omo_[2];
#pragma unroll
    for (int t = 0; t < 2; t++) {
        const int o = t * 16 + l15;
        if (o < OUT_N) {
            ao_[t]  = expf(__fdiv_rn(-1.f, taumo[o]));
            omo_[t] = __fsub_rn(1.f, ao_[t]);
        } else { ao_[t] = 0.f; omo_[t] = 0.f; }
    }

    float mem[2][4], bbv[2][4], spkv[2][4], z[2][4];
#pragma unroll
    for (int t = 0; t < 2; t++)
#pragma unroll
        for (int j = 0; j < 4; j++) {
            mem[t][j] = 0.f; bbv[t][j] = 0.01f; spkv[t][j] = 0.f; z[t][j] = 0.f;
        }

    // pv prefetch for s=0
    float pv[2][4];
    {
        const int srow = fw ? 0 : (S_LEN - 1);
#pragma unroll
        for (int t = 0; t < 2; t++)
#pragma unroll
            for (int j = 0; j < 4; j++)
                pv[t][j] = P[((size_t)(b0 + l4 * 4 + j) * S_LEN + srow) * 512
                             + d * HID + w * 32 + t * 16 + l15];
    }

    for (int s = 0; s < S_LEN; s++) {
        const int cur = s & 1, prev = cur ^ 1;

        // prefetch next step's projection (hidden under this step's work)
        float pvn[2][4];
        {
            const int sn  = s + 1;
            const int srn = fw ? (sn < S_LEN ? sn : S_LEN - 1)
                               : (sn < S_LEN ? (S_LEN - 1 - sn) : 0);
#pragma unroll
            for (int t = 0; t < 2; t++)
#pragma unroll
                for (int j = 0; j < 4; j++)
                    pvn[t][j] = P[((size_t)(b0 + l4 * 4 + j) * S_LEN + srn) * 512
                                  + d * HID + w * 32 + t * 16 + l15];
        }

        __syncthreads();   // Sp[prev] complete from all waves

        // ---- recurrent GEMM: D[batch][col] += spk(prev) @ W_rec
        f32x4 acc[2];
        acc[0] = (f32x4){0.f, 0.f, 0.f, 0.f};
        acc[1] = (f32x4){0.f, 0.f, 0.f, 0.f};
#pragma unroll
        for (int kt = 0; kt < 8; kt++) {
            const bf16x8 a = *(const bf16x8*)&Sp[prev][l15][kt * 32 + l4 * 8];
            acc[0] = __builtin_amdgcn_mfma_f32_16x16x32_bf16(a, whf[kt][0], acc[0], 0, 0, 0);
            acc[0] = __builtin_amdgcn_mfma_f32_16x16x32_bf16(a, wlf[kt][0], acc[0], 0, 0, 0);
            acc[1] = __builtin_amdgcn_mfma_f32_16x16x32_bf16(a, whf[kt][1], acc[1], 0, 0, 0);
            acc[1] = __builtin_amdgcn_mfma_f32_16x16x32_bf16(a, wlf[kt][1], acc[1], 0, 0, 0);
        }

        // ---- adaptive-LIF update on the C/D fragment (exact ref rounding)
#pragma unroll
        for (int t = 0; t < 2; t++) {
#pragma unroll
            for (int j = 0; j < 4; j++) {
                const float dd = __fadd_rn(__fadd_rn(pv[t][j], acc[t][j]), brc_[t]);
                bbv[t][j] = __fadd_rn(__fmul_rn(ro_[t], bbv[t][j]),
                                      __fmul_rn(omR_[t], spkv[t][j]));
                const float thr = __fadd_rn(0.01f, __fmul_rn(1.8f, bbv[t][j]));
                mem[t][j] = __fsub_rn(
                    __fadd_rn(__fmul_rn(mem[t][j], alpha_[t]),
                              __fmul_rn(omA_[t], dd)),
                    __fmul_rn(thr, spkv[t][j]));
                const bool sp = __fsub_rn(mem[t][j], thr) > 0.f;
                spkv[t][j] = sp ? 1.f : 0.f;
                Sp[cur][l4 * 4 + j][w * 32 + t * 16 + l15] =
                    sp ? (ushort)0x3F80 : (ushort)0;
            }
        }

        // make own-wave spike writes visible to own-wave cross-lane reads
        asm volatile("s_waitcnt lgkmcnt(0)" ::: "memory");
        __builtin_amdgcn_sched_barrier(0);

        // ---- readout partial: S[batch][o] = spk_w(cur) @ Wout_w  (this
        // wave's 32-col k-slice only; linear integrator split by k-chunks)
        {
            const bf16x8 ar = *(const bf16x8*)&Sp[cur][l15][w * 32 + l4 * 8];
            f32x4 S0 = (f32x4){0.f, 0.f, 0.f, 0.f};
            f32x4 S1 = (f32x4){0.f, 0.f, 0.f, 0.f};
            S0 = __builtin_amdgcn_mfma_f32_16x16x32_bf16(ar, woh[0], S0, 0, 0, 0);
            S0 = __builtin_amdgcn_mfma_f32_16x16x32_bf16(ar, wol[0], S0, 0, 0, 0);
            S1 = __builtin_amdgcn_mfma_f32_16x16x32_bf16(ar, woh[1], S1, 0, 0, 0);
            S1 = __builtin_amdgcn_mfma_f32_16x16x32_bf16(ar, wol[1], S1, 0, 0, 0);
#pragma unroll
            for (int j = 0; j < 4; j++) {
                z[0][j] = __fmaf_rn(ao_[0], z[0][j], __fmul_rn(omo_[0], S0[j]));
                z[1][j] = __fmaf_rn(ao_[1], z[1][j], __fmul_rn(omo_[1], S1[j]));
            }
        }

#pragma unroll
        for (int t = 0; t < 2; t++)
#pragma unroll
            for (int j = 0; j < 4; j++) pv[t][j] = pvn[t][j];
    }

    __syncthreads();   // all waves done reading P rows we now overwrite

    // ---- stash per-wave readout partials into consumed P rows
    // region: rows b0*250+0..9, cols [d*256, d*256+256)
    float* stash = Pst + ((size_t)b0 * S_LEN) * 512 + d * HID;
#pragma unroll
    for (int j = 0; j < 4; j++) {
        const int r = l4 * 4 + j;
        const int idx0 = w * 320 + r * 16 + l15;
        stash[(size_t)(idx0 >> 8) * 512 + (idx0 & 255)] = z[0][j];
        if (l15 < 4) {
            const int idx1 = w * 320 + 256 + r * 4 + l15;
            stash[(size_t)(idx1 >> 8) * 512 + (idx1 & 255)] = z[1][j];
        }
    }
}

// ---------------------------------------------------------------------------
// Kernel 3: merge stashed partials (fixed order: d 0..1, w 0..7) + bias
// closed form + log_softmax. One 64-thread block per batch.
// ---------------------------------------------------------------------------
__global__ __launch_bounds__(64) void merge_out(
    const float* __restrict__ Pst, const float* __restrict__ bout,
    const float* __restrict__ taumo, float* __restrict__ out)
{
    const int bb = blockIdx.x;
    const int o  = threadIdx.x;         // active 0..19
    const int g  = bb >> 4, r = bb & 15;

    float val = 0.f, v = -3.0e38f;
    if (o < OUT_N) {
        float tot = 0.f;
#pragma unroll
        for (int d2 = 0; d2 < 2; d2++) {
            const float* stash = Pst + ((size_t)(g * 16) * S_LEN) * 512 + d2 * HID;
#pragma unroll
            for (int w2 = 0; w2 < 8; w2++) {
                const int idx = (o < 16) ? (w2 * 320 + r * 16 + o)
                                         : (w2 * 320 + 256 + r * 4 + (o - 16));
                tot = __fadd_rn(tot, stash[(size_t)(idx >> 8) * 512 + (idx & 255)]);
            }
        }
        const float aS = expf(__fdiv_rn(-(float)S_LEN, taumo[o]));
        val = __fadd_rn(tot, __fmul_rn(bout[o], __fsub_rn(1.f, aS)));
        v = val;
    }
    float mx = v;
#pragma unroll
    for (int d2 = 1; d2 < 64; d2 <<= 1)
        mx = fmaxf(mx, __shfl_xor(mx, d2, 64));
    float e = (o < OUT_N) ? expf(__fsub_rn(val, mx)) : 0.f;
#pragma unroll
    for (int d2 = 1; d2 < 64; d2 <<= 1)
        e += __shfl_xor(e, d2, 64);
    if (o < OUT_N)
        out[(size_t)bb * OUT_N + o] =
            __fsub_rn(__fsub_rn(val, mx), logf(e));
}

// ---------------------------------------------------------------------------
extern "C" void kernel_launch(void* const* d_in, const int* in_sizes, int n_in,
                              void* d_out, int out_size, void* d_ws, size_t ws_size,
                              hipStream_t stream) {
    const float* x         = (const float*)d_in[0];
    const float* W_in_f    = (const float*)d_in[1];
    const float* b_in_f    = (const float*)d_in[2];
    const float* W_rec_f   = (const float*)d_in[3];
    const float* b_rec_f   = (const float*)d_in[4];
    const float* tau_m_f   = (const float*)d_in[5];
    const float* tau_adp_f = (const float*)d_in[6];
    const float* W_in_b    = (const float*)d_in[7];
    const float* b_in_b    = (const float*)d_in[8];
    const float* W_rec_b   = (const float*)d_in[9];
    const float* b_rec_b   = (const float*)d_in[10];
    const float* tau_m_b   = (const float*)d_in[11];
    const float* tau_adp_b = (const float*)d_in[12];
    const float* W_out     = (const float*)d_in[13];
    const float* b_out     = (const float*)d_in[14];
    const float* tau_m_o   = (const float*)d_in[15];
    float* out = (float*)d_out;
    float* P   = (float*)d_ws;

    proj_mfma<<<dim3(4, 500), dim3(256), 0, stream>>>(
        x, W_in_f, W_in_b, b_in_f, b_in_b, P);
    scan_mfma<<<dim3(16, 2), dim3(512), 0, stream>>>(
        P, W_rec_f, b_rec_f, tau_m_f, tau_adp_f,
        W_rec_b, b_rec_b, tau_m_b, tau_adp_b,
        W_out, tau_m_o, P);
    merge_out<<<dim3(BATCH), dim3(64), 0, stream>>>(
        P, b_out, tau_m_o, out);
}